// Round 3
// baseline (778.054 us; speedup 1.0000x reference)
//
#include <hip/hip_runtime.h>
#include <cstddef>

// Fused single-head causal attention. B=4096, T=96, C=256, H=64.
// out = softmax(mask((x@Wq)(x@Wk)^T * C^-0.5)) @ (x@Wv)
//
// v7 = v6 (scratch-free phases 2/3, coalesced epilogue) + deep-pipelined
// phase 1:
//  - BK=64: 4 K-iterations instead of 8; 24 MFMAs per barrier; pack staged as
//    2 x 24 KB ping-pong slices (arena size unchanged -> still 2 blocks/CU).
//  - Counted s_waitcnt vmcnt(4) + raw s_barrier: each iteration issues
//    stage(kt+1) first, then x(kt+1); the bottom-of-iteration wait drains only
//    the stage (issued ~700cy earlier), x loads ride across the barrier and
//    are consumed one full iteration (~900cy) after issue. v6 waited on a
//    stage issued ~300cy earlier and consumed x with <500cy slack -> every
//    one of its 8 barrier events convoy-stalled all 12 waves.
//  - All x prefetch slots are NAMED f32x4 scalars (no arrays, no pointer
//    params): v5's regression traced to runtime-indexed/pointer-accessed
//    prefetch state spilling to scratch (WRITE_SIZE 659 MB).

typedef __bf16 bf16x8 __attribute__((ext_vector_type(8)));
typedef float f32x4 __attribute__((ext_vector_type(4)));

#define GLOAD_LDS16(gp, lp)                                                     \
  __builtin_amdgcn_global_load_lds(                                             \
      (const __attribute__((address_space(1))) void*)(gp),                      \
      (__attribute__((address_space(3))) void*)(lp), 16, 0, 0)

// compile-time memory fence: pins issue order (stage before x-loads) so the
// counted vmcnt(N) is valid; raw s_barrier is IntrNoMem so it needs the
// clobber to stop memory ops crossing it.
#define FENCE() asm volatile("" ::: "memory")
#define WAITVM(N) asm volatile("s_waitcnt vmcnt(" #N ")" ::: "memory")
#define BAR() do { __builtin_amdgcn_s_barrier(); FENCE(); } while (0)

static __device__ __forceinline__ unsigned short f2bf_u16(float f) {
  union { float f; unsigned int u; } c; c.f = f;
  return (unsigned short)((c.u + 0x7FFFu + ((c.u >> 16) & 1u)) >> 16);
}

// ---- weight packing: fp32 [256][64] -> bf16 B-fragment order, kt-major ----
// pack[kt][p][nt][lane][j] = bf16(W_p[32*kt + (lane>>4)*8 + j][16*nt + (lane&15)])
// One kt-slice (3p x 4nt x 64lane x 8) = 12,288 B contiguous.
__global__ void pack_w(const float* __restrict__ Wk, const float* __restrict__ Wq,
                       const float* __restrict__ Wv, unsigned short* __restrict__ pack) {
  int idx = blockIdx.x * blockDim.x + threadIdx.x;  // 6144 total
  if (idx >= 6144) return;
  int lane = idx & 63;
  int t = idx >> 6;          // t = kt*12 + p*4 + nt
  int nt = t & 3;
  int p  = (t >> 2) % 3;
  int kt = t / 12;
  const float* W = (p == 0) ? Wk : (p == 1) ? Wq : Wv;
  int k0 = kt * 32 + (lane >> 4) * 8;
  int n  = nt * 16 + (lane & 15);
  unsigned short* dst = pack + (size_t)idx * 8;
#pragma unroll
  for (int j = 0; j < 8; ++j) dst[j] = f2bf_u16(W[(size_t)(k0 + j) * 64 + n]);
}

// ---------------- fused attention, 2 batches per block ----------------
#define LDK 72    // k buffer row stride (u16)
#define LDP 104   // P / q-scratch row stride (u16)
#define LDV 104   // vT row stride inside recycled k region

__global__ __launch_bounds__(768, 6) void head_fused(
    const float* __restrict__ x, const unsigned short* __restrict__ pack,
    float* __restrict__ out) {
  // One flat LDS arena with phase-based aliasing:
  //   [0, 49152)      : pack ping-pong, 2 x 24576 B        (phase 1 only)
  //   [0, 39936)      : SA = q-scratch then P, 2x96xLDP u16 (phase 2/3)
  //   [39936, 67584)  : ks2 = k, then vT, 2x96xLDK u16
  //   [67584, 68352)  : rowsum, 2x96 f32
  //   [0, 49152)      : per-wave O staging tiles, 12 x 4096 B (epilogue)
  __shared__ __attribute__((aligned(16))) unsigned char smem[68352];
  unsigned short* SA  = (unsigned short*)smem;
  unsigned short* ks2 = (unsigned short*)(smem + 39936);
  float*          rsm = (float*)(smem + 67584);

  const int w    = threadIdx.x >> 6;   // 0..11
  const int half = w >= 6;
  const int w6   = w - 6 * half;       // row-tile 0..5
  const int lane = threadIdx.x & 63;
  const int lo   = lane & 15;
  const int hi   = lane >> 4;

  const int bb = 2 * blockIdx.x + half;
  const float* __restrict__ xb = x + (size_t)bb * (96 * 256);

  unsigned short* SAh  = SA  + half * (96 * LDP);
  unsigned short* ks2h = ks2 + half * (96 * LDK);
  float*          rsh  = rsm + half * 96;

  // ---- Phase 1: [k|q|v] = x @ [Wk|Wq|Wv], BK=64, counted-vmcnt dbuf ----
  f32x4 acc[3][4];
#pragma unroll
  for (int p = 0; p < 3; ++p)
#pragma unroll
    for (int nt = 0; nt < 4; ++nt) acc[p][nt] = (f32x4){0.f, 0.f, 0.f, 0.f};

  const int am = 16 * w6 + lo;                       // x row this lane supplies
  const float* xrow = xb + (size_t)am * 256 + hi * 8;

  // stage 24 KB chunk J (slices 2J, 2J+1) into dbuf half at BUFOFS.
#define STAGE64(J, BUFOFS) do {                                                       \
    const char* g_ = (const char*)pack + (size_t)(J) * 24576                          \
                     + (size_t)threadIdx.x * 16;                                      \
    GLOAD_LDS16(g_,         smem + (BUFOFS) + (size_t)w * 1024);                      \
    GLOAD_LDS16(g_ + 12288, smem + (BUFOFS) + 12288 + (size_t)w * 1024);              \
    FENCE();                                                                          \
  } while (0)

  // load x chunk J (64 floats per lane-row, this lane's 4 f32x4 pieces) into
  // four NAMED slot registers (never arrays -> never scratch).
#define XLOAD4(P0, P1, P2, P3, J) do {             \
    const float* xp_ = xrow + (J) * 64;            \
    P0 = *(const f32x4*)(xp_);                     \
    P1 = *(const f32x4*)(xp_ + 4);                 \
    P2 = *(const f32x4*)(xp_ + 32);                \
    P3 = *(const f32x4*)(xp_ + 36);                \
    FENCE();                                       \
  } while (0)

  union bfu { bf16x8 v; unsigned short u[8]; };

#define CONV(P0, P1, P2, P3, AF0, AF1) do {        \
    _Pragma("unroll")                              \
    for (int j_ = 0; j_ < 4; ++j_) {               \
      AF0.u[j_]     = f2bf_u16(P0[j_]);            \
      AF0.u[4 + j_] = f2bf_u16(P1[j_]);            \
      AF1.u[j_]     = f2bf_u16(P2[j_]);            \
      AF1.u[4 + j_] = f2bf_u16(P3[j_]);            \
    }                                              \
  } while (0)

#define MFMA24(BUFOFS, AF0, AF1) do {                                                  \
    const unsigned short* pb_ = (const unsigned short*)(smem + (BUFOFS));              \
    _Pragma("unroll")                                                                  \
    for (int p_ = 0; p_ < 3; ++p_)                                                     \
      _Pragma("unroll")                                                                \
      for (int nt_ = 0; nt_ < 4; ++nt_) {                                              \
        bf16x8 b_ = *(const bf16x8*)(pb_ + ((p_ * 4 + nt_) * 64 + lane) * 8);          \
        acc[p_][nt_] = __builtin_amdgcn_mfma_f32_16x16x32_bf16(AF0, b_,                \
                                                               acc[p_][nt_], 0, 0, 0);\
      }                                                                                \
    const unsigned short* pc_ = (const unsigned short*)(smem + (BUFOFS) + 12288);      \
    _Pragma("unroll")                                                                  \
    for (int p_ = 0; p_ < 3; ++p_)                                                     \
      _Pragma("unroll")                                                                \
      for (int nt_ = 0; nt_ < 4; ++nt_) {                                              \
        bf16x8 b_ = *(const bf16x8*)(pc_ + ((p_ * 4 + nt_) * 64 + lane) * 8);          \
        acc[p_][nt_] = __builtin_amdgcn_mfma_f32_16x16x32_bf16(AF1, b_,                \
                                                               acc[p_][nt_], 0, 0, 0);\
      }                                                                                \
  } while (0)

  f32x4 A0, A1, A2, A3;   // x chunk slot A
  f32x4 B0, B1, B2, B3;   // x chunk slot B

  // prologue: queue = [stageA(2), xA(4)]; drain stage only, x rides the barrier
  STAGE64(0, 0);
  XLOAD4(A0, A1, A2, A3, 0);
  WAITVM(4);
  BAR();

  { // it 0: compute chunk0 (buf0); stage chunk1 -> buf1; prefetch x chunk1
    STAGE64(1, 24576);
    XLOAD4(B0, B1, B2, B3, 1);
    bfu af0, af1; CONV(A0, A1, A2, A3, af0, af1);   // compiler waits x0 here
    MFMA24(0, af0.v, af1.v);
    WAITVM(4);          // drains stage1 (issued ~full iter ago); x1 in flight
    BAR();
  }
  { // it 1: compute chunk1 (buf1); stage chunk2 -> buf0; prefetch x chunk2
    STAGE64(2, 0);
    XLOAD4(A0, A1, A2, A3, 2);
    bfu af0, af1; CONV(B0, B1, B2, B3, af0, af1);
    MFMA24(24576, af0.v, af1.v);
    WAITVM(4);          // drains stage2; x2 in flight
    BAR();
  }
  { // it 2: compute chunk2 (buf0); stage chunk3 -> buf1; prefetch x chunk3
    STAGE64(3, 24576);
    XLOAD4(B0, B1, B2, B3, 3);
    bfu af0, af1; CONV(A0, A1, A2, A3, af0, af1);
    MFMA24(0, af0.v, af1.v);
    WAITVM(4);          // drains stage3; x3 in flight
    BAR();
  }
  { // it 3: compute chunk3 (buf1); nothing left to issue
    bfu af0, af1; CONV(B0, B1, B2, B3, af0, af1);   // compiler drains x3
    MFMA24(24576, af0.v, af1.v);
    __syncthreads();    // all pack-LDS reads drained before SA/ks2 overwrite
  }

  // D layout: row = 16*w6 + hi*4 + r, col = 16*nt + lo.  acc[0]=k, [1]=q, [2]=v.
  unsigned short vv[16];  // v D-frags, carried in regs to phase 3 (static idx)
#pragma unroll
  for (int nt = 0; nt < 4; ++nt) {
#pragma unroll
    for (int r = 0; r < 4; ++r) {
      int row = 16 * w6 + hi * 4 + r;
      int col = 16 * nt + lo;
      ks2h[row * LDK + col] = f2bf_u16(acc[0][nt][r]);  // k
      SAh [row * LDP + col] = f2bf_u16(acc[1][nt][r]);  // q (scratch in P buf)
      vv[nt * 4 + r] = f2bf_u16(acc[2][nt][r]);         // v stays in regs
    }
  }
  __syncthreads();  // k,q visible

  // ---- Phase 2: S = q k^T / 16, causal mask, row softmax, P -> SA ----
  // Fully static unroll: sacc/pr stay in VGPRs (runtime-indexed arrays go to
  // scratch -> was v4/v5's 250-550 MB of excess HBM traffic).
  f32x4 sacc[6];
#pragma unroll
  for (int jt = 0; jt < 6; ++jt) sacc[jt] = (f32x4){0.f, 0.f, 0.f, 0.f};

  bf16x8 qf0 = *(const bf16x8*)(SAh + (16 * w6 + lo) * LDP + hi * 8);
  bf16x8 qf1 = *(const bf16x8*)(SAh + (16 * w6 + lo) * LDP + 32 + hi * 8);
#pragma unroll
  for (int jt = 0; jt < 6; ++jt) {
    if (jt <= w6) {   // wave-uniform branch; indices stay compile-time
      bf16x8 kf0 = *(const bf16x8*)(ks2h + (16 * jt + lo) * LDK + hi * 8);
      bf16x8 kf1 = *(const bf16x8*)(ks2h + (16 * jt + lo) * LDK + 32 + hi * 8);
      sacc[jt] = __builtin_amdgcn_mfma_f32_16x16x32_bf16(qf0, kf0, sacc[jt], 0, 0, 0);
      sacc[jt] = __builtin_amdgcn_mfma_f32_16x16x32_bf16(qf1, kf1, sacc[jt], 0, 0, 0);
    }
  }

  // Uniform softmax over all 6 tiles: for jt > w6, col > row always, so the
  // causal mask gives -1e30 -> exp -> 0 (sacc there is the zero init).
#pragma unroll
  for (int r = 0; r < 4; ++r) {
    int row = 16 * w6 + hi * 4 + r;
    float pr[6];
    float mx = -1e30f;
#pragma unroll
    for (int jt = 0; jt < 6; ++jt) {
      int col = 16 * jt + lo;
      float s = sacc[jt][r] * 0.0625f;           // * C^-0.5
      s = (col <= row) ? s : -1e30f;
      pr[jt] = s;
      mx = fmaxf(mx, s);
    }
#pragma unroll
    for (int off = 1; off < 16; off <<= 1) mx = fmaxf(mx, __shfl_xor(mx, off, 64));
    float sum = 0.f;
#pragma unroll
    for (int jt = 0; jt < 6; ++jt) {
      float p = __expf(pr[jt] - mx);
      pr[jt] = p;
      sum += p;
    }
#pragma unroll
    for (int off = 1; off < 16; off <<= 1) sum += __shfl_xor(sum, off, 64);
#pragma unroll
    for (int jt = 0; jt < 6; ++jt)
      SAh[row * LDP + 16 * jt + lo] = f2bf_u16(pr[jt]);
    if (lo == 0) rsh[row] = sum;
  }
  __syncthreads();  // all k reads done; P,rowsum visible

  // ---- recycle k buffer as vT ----
  unsigned short* vT = ks2h;  // [64][LDV], 64*104 u16 fits in 96*72 u16
#pragma unroll
  for (int nt = 0; nt < 4; ++nt) {
#pragma unroll
    for (int r = 0; r < 4; ++r) {
      int row = 16 * w6 + hi * 4 + r;
      int col = 16 * nt + lo;
      vT[col * LDV + row] = vv[nt * 4 + r];
    }
  }
  __syncthreads();  // vT visible

  // ---- Phase 3: O = P @ v ----
  f32x4 oacc[4];
#pragma unroll
  for (int nt = 0; nt < 4; ++nt) oacc[nt] = (f32x4){0.f, 0.f, 0.f, 0.f};

  const int ksmax = (16 * w6 + 15) >> 5;  // skip all-zero K-chunks (causal)
  for (int ks = 0; ks <= ksmax; ++ks) {   // oacc indices static -> regs
    bf16x8 pf = *(const bf16x8*)(SAh + (16 * w6 + lo) * LDP + ks * 32 + hi * 8);
#pragma unroll
    for (int nt = 0; nt < 4; ++nt) {
      bf16x8 vf = *(const bf16x8*)(vT + (16 * nt + lo) * LDV + ks * 32 + hi * 8);
      oacc[nt] = __builtin_amdgcn_mfma_f32_16x16x32_bf16(pf, vf, oacc[nt], 0, 0, 0);
    }
  }

  // ---- epilogue: normalize, per-wave LDS tile, full-row dwordx4 stores ----
  __syncthreads();  // all P/vT reads complete; arena reusable for O tiles
  float* ot = (float*)(smem + (size_t)w * 4096);   // wave-private [16][64] f32
#pragma unroll
  for (int r = 0; r < 4; ++r) {
    float inv = 1.0f / rsh[16 * w6 + hi * 4 + r];
#pragma unroll
    for (int nt = 0; nt < 4; ++nt)
      ot[(hi * 4 + r) * 64 + 16 * nt + lo] = oacc[nt][r] * inv;
  }
  // wave-private tile: no barrier needed between write and read-back.
  float* __restrict__ ob = out + (size_t)bb * (96 * 64);
#pragma unroll
  for (int i = 0; i < 4; ++i) {
    f32x4 o4 = *(const f32x4*)(ot + (i * 4 + hi) * 64 + lo * 4);
    *(f32x4*)(ob + (size_t)(16 * w6 + i * 4 + hi) * 64 + lo * 4) = o4;
  }
}

extern "C" void kernel_launch(void* const* d_in, const int* in_sizes, int n_in,
                              void* d_out, int out_size, void* d_ws, size_t ws_size,
                              hipStream_t stream) {
  const float* x  = (const float*)d_in[0];
  const float* Wk = (const float*)d_in[1];
  const float* Wq = (const float*)d_in[2];
  const float* Wv = (const float*)d_in[3];
  float* out = (float*)d_out;
  unsigned short* pack = (unsigned short*)d_ws;  // 96 KB, kt-major slices

  const int B = in_sizes[0] / (96 * 256);

  pack_w<<<24, 256, 0, stream>>>(Wk, Wq, Wv, pack);
  head_fused<<<B / 2, 768, 0, stream>>>(x, pack, out);
}